// Round 3
// baseline (13426.289 us; speedup 1.0000x reference)
//
#include <hip/hip_runtime.h>

#define Bsz  128
#define Tlen 96
#define Edim 512
#define Ddim 512
#define Adim 512
#define EMBd 512
#define Vdim 4096

__device__ __forceinline__ float sigm(float x) { return 1.0f / (1.0f + expf(-x)); }

// ---------------------------------------------------------------------------
// Stable descending sort by length (matches jnp.argsort(-lens), stable).
__global__ void k_sort(const int* __restrict__ lens, int* __restrict__ order,
                       int* __restrict__ lens_s) {
    __shared__ int L[Bsz];
    int j = threadIdx.x;
    L[j] = lens[j];
    __syncthreads();
    int lj = L[j];
    int rank = 0;
    for (int m = 0; m < Bsz; ++m) {
        int lm = L[m];
        if (lm > lj || (lm == lj && m < j)) rank++;
    }
    order[rank] = j;
    lens_s[rank] = lj;
}

// Gather sorted encoder rows.
__global__ void k_gather(const float* __restrict__ enc_in,
                         const int* __restrict__ order, float* __restrict__ enc_s) {
    int i = blockIdx.x;
    int src = order[i];
    for (int d = threadIdx.x; d < Edim; d += 256)
        enc_s[i * Edim + d] = enc_in[src * Edim + d];
}

// ---------------------------------------------------------------------------
// Tiled fp32 matmul: block computes 64x64 tile of  act[128xK] @ W[NxK]^T.
// act fp32 row-major, W fp32 row-major [N][K] (pass pointer pre-offset to tile row).
__device__ __forceinline__ void mm_tile(const float* __restrict__ act,
                                        const float* __restrict__ W,
                                        int K, int i0, float acc[4][4]) {
    __shared__ float sA[64][17];
    __shared__ float sB[64][17];
    int tid = threadIdx.x;
    int tx = tid & 15, ty = tid >> 4;
    for (int k0 = 0; k0 < K; k0 += 16) {
        {
            int idx = tid * 4;
            int row = idx >> 4;
            int kk = idx & 15;
            const float* p = act + (size_t)(i0 + row) * K + k0 + kk;
            float4 v = *reinterpret_cast<const float4*>(p);
            sA[row][kk + 0] = v.x; sA[row][kk + 1] = v.y;
            sA[row][kk + 2] = v.z; sA[row][kk + 3] = v.w;
        }
        {
            int idx = tid * 4;
            int row = idx >> 4;
            int kk = idx & 15;
            const float* p = W + (size_t)row * K + k0 + kk;
            float4 v = *reinterpret_cast<const float4*>(p);
            sB[row][kk + 0] = v.x; sB[row][kk + 1] = v.y;
            sB[row][kk + 2] = v.z; sB[row][kk + 3] = v.w;
        }
        __syncthreads();
#pragma unroll
        for (int kk = 0; kk < 16; ++kk) {
            float a[4], b[4];
#pragma unroll
            for (int r = 0; r < 4; ++r) a[r] = sA[ty * 4 + r][kk];
#pragma unroll
            for (int cidx = 0; cidx < 4; ++cidx) b[cidx] = sB[tx * 4 + cidx][kk];
#pragma unroll
            for (int r = 0; r < 4; ++r)
#pragma unroll
                for (int cidx = 0; cidx < 4; ++cidx)
                    acc[r][cidx] += a[r] * b[cidx];
        }
        __syncthreads();
    }
}

// ---------------------------------------------------------------------------
// Init: h0 | c0 | att1  =  enc_s @ [W_init_h | W_init_c | W_enc]^T + biases
__global__ __launch_bounds__(256) void k_init(
    const float* __restrict__ enc_s,
    const float* __restrict__ W_init_h, const float* __restrict__ b_init_h,
    const float* __restrict__ W_init_c, const float* __restrict__ b_init_c,
    const float* __restrict__ W_enc, const float* __restrict__ b_enc,
    float* __restrict__ h, float* __restrict__ c, float* __restrict__ att1) {
    int j0 = blockIdx.x * 64;
    int i0 = blockIdx.y * 64;
    const float* W; const float* bias; float* out; int jl;
    if (j0 < 512)       { W = W_init_h; bias = b_init_h; out = h;    jl = j0; }
    else if (j0 < 1024) { W = W_init_c; bias = b_init_c; out = c;    jl = j0 - 512; }
    else                { W = W_enc;    bias = b_enc;    out = att1; jl = j0 - 1024; }
    float acc[4][4] = {};
    mm_tile(enc_s, W + (size_t)jl * Edim, Edim, i0, acc);
    int tx = threadIdx.x & 15, ty = threadIdx.x >> 4;
#pragma unroll
    for (int r = 0; r < 4; ++r)
#pragma unroll
        for (int cc = 0; cc < 4; ++cc) {
            int i = i0 + ty * 4 + r, j = jl + tx * 4 + cc;
            out[i * 512 + j] = acc[r][cc] + bias[j];
        }
}

// ---------------------------------------------------------------------------
// Step A: from h (state after step t-1) compute:
//   preds(t-1) = h @ W_fc^T + b_fc      (-> out, zero where invalid; skip at t==0)
//   att2(t)    = h @ W_dec^T + b_dec
//   gate(t)    = sigmoid(h @ W_fbeta^T + b_fbeta)
//   hh(t)      = h @ W_hh^T + b_hh
__global__ __launch_bounds__(256) void k_stepA(
    const float* __restrict__ h,
    const float* __restrict__ W_fc, const float* __restrict__ b_fc,
    const float* __restrict__ W_dec, const float* __restrict__ b_dec,
    const float* __restrict__ W_fbeta, const float* __restrict__ b_fbeta,
    const float* __restrict__ W_hh, const float* __restrict__ b_hh,
    float* __restrict__ att2, float* __restrict__ gate, float* __restrict__ hh,
    float* __restrict__ out, const int* __restrict__ lens_s, int t) {
    int j0 = blockIdx.x * 64;
    int i0 = blockIdx.y * 64;
    int tx = threadIdx.x & 15, ty = threadIdx.x >> 4;
    if (j0 < 4096) {
        if (t == 0) return;
        float acc[4][4] = {};
        mm_tile(h, W_fc + (size_t)j0 * Ddim, Ddim, i0, acc);
        int tt = t - 1;
#pragma unroll
        for (int r = 0; r < 4; ++r) {
            int i = i0 + ty * 4 + r;
            bool valid = tt < lens_s[i];
#pragma unroll
            for (int cc = 0; cc < 4; ++cc) {
                int j = j0 + tx * 4 + cc;
                float v = valid ? (acc[r][cc] + b_fc[j]) : 0.0f;
                out[((size_t)i * Tlen + tt) * Vdim + j] = v;
            }
        }
    } else if (j0 < 4608) {
        float acc[4][4] = {};
        int jl = j0 - 4096;
        mm_tile(h, W_dec + (size_t)jl * Ddim, Ddim, i0, acc);
#pragma unroll
        for (int r = 0; r < 4; ++r)
#pragma unroll
            for (int cc = 0; cc < 4; ++cc) {
                int i = i0 + ty * 4 + r, j = jl + tx * 4 + cc;
                att2[i * 512 + j] = acc[r][cc] + b_dec[j];
            }
    } else if (j0 < 5120) {
        float acc[4][4] = {};
        int jl = j0 - 4608;
        mm_tile(h, W_fbeta + (size_t)jl * Ddim, Ddim, i0, acc);
#pragma unroll
        for (int r = 0; r < 4; ++r)
#pragma unroll
            for (int cc = 0; cc < 4; ++cc) {
                int i = i0 + ty * 4 + r, j = jl + tx * 4 + cc;
                gate[i * 512 + j] = sigm(acc[r][cc] + b_fbeta[j]);
            }
    } else {
        float acc[4][4] = {};
        int jl = j0 - 5120;
        mm_tile(h, W_hh + (size_t)jl * Ddim, Ddim, i0, acc);
#pragma unroll
        for (int r = 0; r < 4; ++r)
#pragma unroll
            for (int cc = 0; cc < 4; ++cc) {
                int i = i0 + ty * 4 + r, j = jl + tx * 4 + cc;
                hh[i * 2048 + j] = acc[r][cc] + b_hh[j];
            }
    }
}

// ---------------------------------------------------------------------------
// Step B: scores -> softmax (over KEYS j, masked by t >= lens_s[j]) -> awe,
// gate multiply, build x = [emb_t, gate*awe]
__global__ __launch_bounds__(256) void k_stepB(
    const float* __restrict__ att1, const float* __restrict__ att2,
    const float* __restrict__ enc_s,
    const float* __restrict__ W_full, const float* __restrict__ b_full,
    const float* __restrict__ gate, const float* __restrict__ emb_table,
    const int* __restrict__ caps, const int* __restrict__ order,
    const int* __restrict__ lens_s, float* __restrict__ x, int t) {
    int i = blockIdx.x;
    int tid = threadIdx.x;
    __shared__ float sA2[512];
    __shared__ float sWF[512];
    __shared__ float sSC[128];
    __shared__ float sRed[2];
    for (int d = tid; d < 512; d += 256) {
        sA2[d] = att2[i * 512 + d];
        sWF[d] = W_full[d];
    }
    __syncthreads();
    if (tid < 128) {
        int j = tid;
        const float* a1 = att1 + j * 512;
        float acc = 0.0f;
        for (int k = 0; k < 512; ++k) {
            float v = a1[k] + sA2[k];
            acc += fmaxf(v, 0.0f) * sWF[k];
        }
        float sc = acc + b_full[0];
        if (t >= lens_s[j]) sc = -1000000000.0f;
        sSC[j] = sc;
    }
    __syncthreads();
    if (tid < 64) {
        float m = fmaxf(sSC[tid], sSC[tid + 64]);
        for (int o = 32; o; o >>= 1) m = fmaxf(m, __shfl_down(m, o));
        if (tid == 0) sRed[0] = m;
    }
    __syncthreads();
    if (tid < 128) sSC[tid] = expf(sSC[tid] - sRed[0]);
    __syncthreads();
    if (tid < 64) {
        float s = sSC[tid] + sSC[tid + 64];
        for (int o = 32; o; o >>= 1) s += __shfl_down(s, o);
        if (tid == 0) sRed[1] = s;
    }
    __syncthreads();
    float inv = 1.0f / sRed[1];
    int cap = caps[order[i] * Tlen + t];
    for (int d = tid; d < 512; d += 256) {
        float acc = 0.0f;
        for (int j = 0; j < 128; ++j) acc += sSC[j] * enc_s[j * 512 + d];
        acc *= inv;
        x[i * 1024 + 512 + d] = gate[i * 512 + d] * acc;
        x[i * 1024 + d] = emb_table[(size_t)cap * EMBd + d];
    }
}

// ---------------------------------------------------------------------------
// Step C: gates = x @ W_ih^T + b_ih + hh   (hh already contains b_hh)
__global__ __launch_bounds__(256) void k_stepC(
    const float* __restrict__ x, const float* __restrict__ W_ih,
    const float* __restrict__ b_ih, const float* __restrict__ hh,
    float* __restrict__ gates) {
    int j0 = blockIdx.x * 64;
    int i0 = blockIdx.y * 64;
    float acc[4][4] = {};
    mm_tile(x, W_ih + (size_t)j0 * 1024, 1024, i0, acc);
    int tx = threadIdx.x & 15, ty = threadIdx.x >> 4;
#pragma unroll
    for (int r = 0; r < 4; ++r)
#pragma unroll
        for (int cc = 0; cc < 4; ++cc) {
            int i = i0 + ty * 4 + r, j = j0 + tx * 4 + cc;
            gates[i * 2048 + j] = acc[r][cc] + b_ih[j] + hh[i * 2048 + j];
        }
}

// ---------------------------------------------------------------------------
// LSTM elementwise update; only rows valid at t update h/c.
__global__ void k_lstm(const float* __restrict__ gates, float* __restrict__ h,
                       float* __restrict__ c, const int* __restrict__ lens_s, int t) {
    int idx = blockIdx.x * 256 + threadIdx.x;  // < 128*512
    int i = idx >> 9, d = idx & 511;
    if (t >= lens_s[i]) return;
    float gi = sigm(gates[i * 2048 + d]);
    float gf = sigm(gates[i * 2048 + 512 + d]);
    float gg = tanhf(gates[i * 2048 + 1024 + d]);
    float go = sigm(gates[i * 2048 + 1536 + d]);
    float cn = gf * c[idx] + gi * gg;
    float hn = go * tanhf(cn);
    c[idx] = cn;
    h[idx] = hn;
}

// ---------------------------------------------------------------------------
extern "C" void kernel_launch(void* const* d_in, const int* in_sizes, int n_in,
                              void* d_out, int out_size, void* d_ws, size_t ws_size,
                              hipStream_t stream) {
    const float* encoder_out = (const float*)d_in[0];
    const int* caps = (const int*)d_in[1];
    const int* lens = (const int*)d_in[2];
    const float* W_enc = (const float*)d_in[3];
    const float* b_enc = (const float*)d_in[4];
    const float* W_dec = (const float*)d_in[5];
    const float* b_dec = (const float*)d_in[6];
    const float* W_full = (const float*)d_in[7];
    const float* b_full = (const float*)d_in[8];
    const float* W_init_h = (const float*)d_in[9];
    const float* b_init_h = (const float*)d_in[10];
    const float* W_init_c = (const float*)d_in[11];
    const float* b_init_c = (const float*)d_in[12];
    const float* W_fbeta = (const float*)d_in[13];
    const float* b_fbeta = (const float*)d_in[14];
    const float* W_fc = (const float*)d_in[15];
    const float* b_fc = (const float*)d_in[16];
    const float* emb_table = (const float*)d_in[17];
    const float* W_ih = (const float*)d_in[18];
    const float* b_ih = (const float*)d_in[19];
    const float* W_hh = (const float*)d_in[20];
    const float* b_hh = (const float*)d_in[21];
    float* out = (float*)d_out;

    char* p = (char*)d_ws;
    auto alloc = [&](size_t bytes) {
        void* r = (void*)p;
        p += (bytes + 255) & ~(size_t)255;
        return r;
    };
    int* order = (int*)alloc(Bsz * 4);
    int* lens_s = (int*)alloc(Bsz * 4);
    float* enc_s = (float*)alloc(Bsz * Edim * 4);
    float* att1 = (float*)alloc(Bsz * Adim * 4);
    float* h = (float*)alloc(Bsz * Ddim * 4);
    float* c = (float*)alloc(Bsz * Ddim * 4);
    float* att2 = (float*)alloc(Bsz * Adim * 4);
    float* gate = (float*)alloc(Bsz * Ddim * 4);
    float* hh = (float*)alloc(Bsz * 2048 * 4);
    float* x = (float*)alloc(Bsz * 1024 * 4);
    float* gates = (float*)alloc(Bsz * 2048 * 4);

    k_sort<<<1, 128, 0, stream>>>(lens, order, lens_s);
    k_gather<<<Bsz, 256, 0, stream>>>(encoder_out, order, enc_s);
    k_init<<<dim3(24, 2), 256, 0, stream>>>(enc_s, W_init_h, b_init_h, W_init_c,
                                            b_init_c, W_enc, b_enc, h, c, att1);
    for (int t = 0; t < Tlen; ++t) {
        k_stepA<<<dim3(112, 2), 256, 0, stream>>>(h, W_fc, b_fc, W_dec, b_dec,
                                                  W_fbeta, b_fbeta, W_hh, b_hh,
                                                  att2, gate, hh, out, lens_s, t);
        k_stepB<<<Bsz, 256, 0, stream>>>(att1, att2, enc_s, W_full, b_full, gate,
                                         emb_table, caps, order, lens_s, x, t);
        k_stepC<<<dim3(32, 2), 256, 0, stream>>>(x, W_ih, b_ih, hh, gates);
        k_lstm<<<256, 256, 0, stream>>>(gates, h, c, lens_s, t);
    }
    // final preds(95): only the W_fc segment
    k_stepA<<<dim3(64, 2), 256, 0, stream>>>(h, W_fc, b_fc, W_dec, b_dec, W_fbeta,
                                             b_fbeta, W_hh, b_hh, att2, gate, hh,
                                             out, lens_s, Tlen);
}

// Round 4
// 13234.760 us; speedup vs baseline: 1.0145x; 1.0145x over previous
//
#include <hip/hip_runtime.h>

#define Bsz  128
#define Tlen 96
#define Edim 512
#define Ddim 512
#define Adim 512
#define EMBd 512
#define Vdim 4096

typedef __attribute__((ext_vector_type(8))) short short8v;
typedef __attribute__((ext_vector_type(4))) float f32x4;

__device__ __forceinline__ float sigm(float x) { return 1.0f / (1.0f + expf(-x)); }
__device__ __forceinline__ unsigned short f2bf(float f) {
    unsigned int x = __float_as_uint(f);
    unsigned int r = (x + 0x7FFFu + ((x >> 16) & 1u)) >> 16;
    return (unsigned short)r;
}

// ---------------------------------------------------------------------------
// Stable descending sort by length (matches jnp.argsort(-lens), stable).
__global__ void k_sort(const int* __restrict__ lens, int* __restrict__ order,
                       int* __restrict__ lens_s) {
    __shared__ int L[Bsz];
    int j = threadIdx.x;
    L[j] = lens[j];
    __syncthreads();
    int lj = L[j];
    int rank = 0;
    for (int m = 0; m < Bsz; ++m) {
        int lm = L[m];
        if (lm > lj || (lm == lj && m < j)) rank++;
    }
    order[rank] = j;
    lens_s[rank] = lj;
}

// Gather sorted encoder rows.
__global__ void k_gather(const float* __restrict__ enc_in,
                         const int* __restrict__ order, float* __restrict__ enc_s) {
    int i = blockIdx.x;
    int src = order[i];
    for (int d = threadIdx.x; d < Edim; d += 256)
        enc_s[i * Edim + d] = enc_in[src * Edim + d];
}

// fp32 -> bf16 weight conversion (W_fc), run every call.
__global__ void k_cvtW(const float* __restrict__ W, unsigned short* __restrict__ O,
                       int n) {
    int i = blockIdx.x * 256 + threadIdx.x;
    if (i < n) O[i] = f2bf(W[i]);
}

// ---------------------------------------------------------------------------
// Tiled fp32 matmul: block computes 64x64 tile of  act[128xK] @ W[NxK]^T.
__device__ __forceinline__ void mm_tile(const float* __restrict__ act,
                                        const float* __restrict__ W,
                                        int K, int i0, float acc[4][4]) {
    __shared__ float sA[64][17];
    __shared__ float sB[64][17];
    int tid = threadIdx.x;
    int tx = tid & 15, ty = tid >> 4;
    for (int k0 = 0; k0 < K; k0 += 16) {
        {
            int idx = tid * 4;
            int row = idx >> 4;
            int kk = idx & 15;
            const float* p = act + (size_t)(i0 + row) * K + k0 + kk;
            float4 v = *reinterpret_cast<const float4*>(p);
            sA[row][kk + 0] = v.x; sA[row][kk + 1] = v.y;
            sA[row][kk + 2] = v.z; sA[row][kk + 3] = v.w;
        }
        {
            int idx = tid * 4;
            int row = idx >> 4;
            int kk = idx & 15;
            const float* p = W + (size_t)row * K + k0 + kk;
            float4 v = *reinterpret_cast<const float4*>(p);
            sB[row][kk + 0] = v.x; sB[row][kk + 1] = v.y;
            sB[row][kk + 2] = v.z; sB[row][kk + 3] = v.w;
        }
        __syncthreads();
#pragma unroll
        for (int kk = 0; kk < 16; ++kk) {
            float a[4], b[4];
#pragma unroll
            for (int r = 0; r < 4; ++r) a[r] = sA[ty * 4 + r][kk];
#pragma unroll
            for (int cidx = 0; cidx < 4; ++cidx) b[cidx] = sB[tx * 4 + cidx][kk];
#pragma unroll
            for (int r = 0; r < 4; ++r)
#pragma unroll
                for (int cidx = 0; cidx < 4; ++cidx)
                    acc[r][cidx] += a[r] * b[cidx];
        }
        __syncthreads();
    }
}

// ---------------------------------------------------------------------------
// Init: h0 | c0 | att1  =  enc_s @ [W_init_h | W_init_c | W_enc]^T + biases
__global__ __launch_bounds__(256) void k_init(
    const float* __restrict__ enc_s,
    const float* __restrict__ W_init_h, const float* __restrict__ b_init_h,
    const float* __restrict__ W_init_c, const float* __restrict__ b_init_c,
    const float* __restrict__ W_enc, const float* __restrict__ b_enc,
    float* __restrict__ h, float* __restrict__ c, float* __restrict__ att1) {
    int j0 = blockIdx.x * 64;
    int i0 = blockIdx.y * 64;
    const float* W; const float* bias; float* out; int jl;
    if (j0 < 512)       { W = W_init_h; bias = b_init_h; out = h;    jl = j0; }
    else if (j0 < 1024) { W = W_init_c; bias = b_init_c; out = c;    jl = j0 - 512; }
    else                { W = W_enc;    bias = b_enc;    out = att1; jl = j0 - 1024; }
    float acc[4][4] = {};
    mm_tile(enc_s, W + (size_t)jl * Edim, Edim, i0, acc);
    int tx = threadIdx.x & 15, ty = threadIdx.x >> 4;
#pragma unroll
    for (int r = 0; r < 4; ++r)
#pragma unroll
        for (int cc = 0; cc < 4; ++cc) {
            int i = i0 + ty * 4 + r, j = jl + tx * 4 + cc;
            out[i * 512 + j] = acc[r][cc] + bias[j];
        }
}

// ---------------------------------------------------------------------------
// Step A (critical path only): att2 | gate | hh from h. 3072 cols.
__global__ __launch_bounds__(256) void k_stepA(
    const float* __restrict__ h,
    const float* __restrict__ W_dec, const float* __restrict__ b_dec,
    const float* __restrict__ W_fbeta, const float* __restrict__ b_fbeta,
    const float* __restrict__ W_hh, const float* __restrict__ b_hh,
    float* __restrict__ att2, float* __restrict__ gate, float* __restrict__ hh) {
    int j0 = blockIdx.x * 64;
    int i0 = blockIdx.y * 64;
    int tx = threadIdx.x & 15, ty = threadIdx.x >> 4;
    if (j0 < 512) {
        float acc[4][4] = {};
        mm_tile(h, W_dec + (size_t)j0 * Ddim, Ddim, i0, acc);
#pragma unroll
        for (int r = 0; r < 4; ++r)
#pragma unroll
            for (int cc = 0; cc < 4; ++cc) {
                int i = i0 + ty * 4 + r, j = j0 + tx * 4 + cc;
                att2[i * 512 + j] = acc[r][cc] + b_dec[j];
            }
    } else if (j0 < 1024) {
        float acc[4][4] = {};
        int jl = j0 - 512;
        mm_tile(h, W_fbeta + (size_t)jl * Ddim, Ddim, i0, acc);
#pragma unroll
        for (int r = 0; r < 4; ++r)
#pragma unroll
            for (int cc = 0; cc < 4; ++cc) {
                int i = i0 + ty * 4 + r, j = jl + tx * 4 + cc;
                gate[i * 512 + j] = sigm(acc[r][cc] + b_fbeta[j]);
            }
    } else {
        float acc[4][4] = {};
        int jl = j0 - 1024;
        mm_tile(h, W_hh + (size_t)jl * Ddim, Ddim, i0, acc);
#pragma unroll
        for (int r = 0; r < 4; ++r)
#pragma unroll
            for (int cc = 0; cc < 4; ++cc) {
                int i = i0 + ty * 4 + r, j = jl + tx * 4 + cc;
                hh[i * 2048 + j] = acc[r][cc] + b_hh[j];
            }
    }
}

// ---------------------------------------------------------------------------
// Step B: scores -> softmax (over KEYS j, masked by t >= lens_s[j]) -> awe,
// gate multiply, build x = [emb_t, gate*awe]
__global__ __launch_bounds__(256) void k_stepB(
    const float* __restrict__ att1, const float* __restrict__ att2,
    const float* __restrict__ enc_s,
    const float* __restrict__ W_full, const float* __restrict__ b_full,
    const float* __restrict__ gate, const float* __restrict__ emb_table,
    const int* __restrict__ caps, const int* __restrict__ order,
    const int* __restrict__ lens_s, float* __restrict__ x, int t) {
    int i = blockIdx.x;
    int tid = threadIdx.x;
    __shared__ float sA2[512];
    __shared__ float sWF[512];
    __shared__ float sSC[128];
    __shared__ float sRed[2];
    for (int d = tid; d < 512; d += 256) {
        sA2[d] = att2[i * 512 + d];
        sWF[d] = W_full[d];
    }
    __syncthreads();
    if (tid < 128) {
        int j = tid;
        const float* a1 = att1 + j * 512;
        float acc = 0.0f;
        for (int k = 0; k < 512; ++k) {
            float v = a1[k] + sA2[k];
            acc += fmaxf(v, 0.0f) * sWF[k];
        }
        float sc = acc + b_full[0];
        if (t >= lens_s[j]) sc = -1000000000.0f;
        sSC[j] = sc;
    }
    __syncthreads();
    if (tid < 64) {
        float m = fmaxf(sSC[tid], sSC[tid + 64]);
        for (int o = 32; o; o >>= 1) m = fmaxf(m, __shfl_down(m, o));
        if (tid == 0) sRed[0] = m;
    }
    __syncthreads();
    if (tid < 128) sSC[tid] = expf(sSC[tid] - sRed[0]);
    __syncthreads();
    if (tid < 64) {
        float s = sSC[tid] + sSC[tid + 64];
        for (int o = 32; o; o >>= 1) s += __shfl_down(s, o);
        if (tid == 0) sRed[1] = s;
    }
    __syncthreads();
    float inv = 1.0f / sRed[1];
    int cap = caps[order[i] * Tlen + t];
    for (int d = tid; d < 512; d += 256) {
        float acc = 0.0f;
        for (int j = 0; j < 128; ++j) acc += sSC[j] * enc_s[j * 512 + d];
        acc *= inv;
        x[i * 1024 + 512 + d] = gate[i * 512 + d] * acc;
        x[i * 1024 + d] = emb_table[(size_t)cap * EMBd + d];
    }
}

// ---------------------------------------------------------------------------
// Step C: gates = x @ W_ih^T + b_ih + hh   (hh already contains b_hh)
__global__ __launch_bounds__(256) void k_stepC(
    const float* __restrict__ x, const float* __restrict__ W_ih,
    const float* __restrict__ b_ih, const float* __restrict__ hh,
    float* __restrict__ gates) {
    int j0 = blockIdx.x * 64;
    int i0 = blockIdx.y * 64;
    float acc[4][4] = {};
    mm_tile(x, W_ih + (size_t)j0 * 1024, 1024, i0, acc);
    int tx = threadIdx.x & 15, ty = threadIdx.x >> 4;
#pragma unroll
    for (int r = 0; r < 4; ++r)
#pragma unroll
        for (int cc = 0; cc < 4; ++cc) {
            int i = i0 + ty * 4 + r, j = j0 + tx * 4 + cc;
            gates[i * 2048 + j] = acc[r][cc] + b_ih[j] + hh[i * 2048 + j];
        }
}

// ---------------------------------------------------------------------------
// LSTM elementwise update; valid rows update h/c; ALWAYS record h into
// bf16 history h_hist[t] (used by the batched preds GEMM at the end).
__global__ void k_lstm(const float* __restrict__ gates, float* __restrict__ h,
                       float* __restrict__ c, const int* __restrict__ lens_s,
                       unsigned short* __restrict__ h_hist, int t) {
    int idx = blockIdx.x * 256 + threadIdx.x;  // < 128*512
    int i = idx >> 9, d = idx & 511;
    float hv;
    if (t < lens_s[i]) {
        float gi = sigm(gates[i * 2048 + d]);
        float gf = sigm(gates[i * 2048 + 512 + d]);
        float gg = tanhf(gates[i * 2048 + 1024 + d]);
        float go = sigm(gates[i * 2048 + 1536 + d]);
        float cn = gf * c[idx] + gi * gg;
        hv = go * tanhf(cn);
        c[idx] = cn;
        h[idx] = hv;
    } else {
        hv = h[idx];
    }
    h_hist[(size_t)t * (Bsz * 512) + idx] = f2bf(hv);
}

// ---------------------------------------------------------------------------
// Batched preds GEMM: out[i,t,:] = h_hist[t,i,:] @ W_fc^T + b_fc (0 if invalid).
// M = Tlen*Bsz = 12288 rows (m = t*128 + i), N = 4096, K = 512. MFMA bf16.
// Block: 256 thr = 4 waves (2x2), tile 128x128; wave tile 64x64 (4x4 frags).
__global__ __launch_bounds__(256) void k_preds(
    const unsigned short* __restrict__ hh16, const unsigned short* __restrict__ wfc16,
    const float* __restrict__ b_fc, const int* __restrict__ lens_s,
    float* __restrict__ out) {
    int nb = blockIdx.x;            // 0..31
    int mb = blockIdx.y;            // 0..95
    int wid = threadIdx.x >> 6;
    int lane = threadIdx.x & 63;
    int wr = wid >> 1, wc = wid & 1;
    int m_wave = mb * 128 + wr * 64;
    int n_wave = nb * 128 + wc * 64;
    int r = lane & 15, g = lane >> 4;
    f32x4 acc[4][4];
#pragma unroll
    for (int a = 0; a < 4; ++a)
#pragma unroll
        for (int b = 0; b < 4; ++b) acc[a][b] = (f32x4){0.f, 0.f, 0.f, 0.f};
    for (int kk = 0; kk < 512; kk += 32) {
        short8v av[4], bv[4];
#pragma unroll
        for (int mf = 0; mf < 4; ++mf)
            av[mf] = *reinterpret_cast<const short8v*>(
                &hh16[(size_t)(m_wave + mf * 16 + r) * 512 + kk + g * 8]);
#pragma unroll
        for (int nf = 0; nf < 4; ++nf)
            bv[nf] = *reinterpret_cast<const short8v*>(
                &wfc16[(size_t)(n_wave + nf * 16 + r) * 512 + kk + g * 8]);
#pragma unroll
        for (int mf = 0; mf < 4; ++mf)
#pragma unroll
            for (int nf = 0; nf < 4; ++nf)
                acc[mf][nf] = __builtin_amdgcn_mfma_f32_16x16x32_bf16(
                    av[mf], bv[nf], acc[mf][nf], 0, 0, 0);
    }
#pragma unroll
    for (int mf = 0; mf < 4; ++mf)
#pragma unroll
        for (int nf = 0; nf < 4; ++nf)
#pragma unroll
            for (int reg = 0; reg < 4; ++reg) {
                int m = m_wave + mf * 16 + g * 4 + reg;  // row = (lane>>4)*4+reg
                int col = n_wave + nf * 16 + r;          // col = lane&15
                int t = m >> 7, i = m & 127;
                bool valid = t < lens_s[i];
                out[((size_t)i * Tlen + t) * Vdim + col] =
                    valid ? acc[mf][nf][reg] + b_fc[col] : 0.0f;
            }
}

// ---------------------------------------------------------------------------
extern "C" void kernel_launch(void* const* d_in, const int* in_sizes, int n_in,
                              void* d_out, int out_size, void* d_ws, size_t ws_size,
                              hipStream_t stream) {
    const float* encoder_out = (const float*)d_in[0];
    const int* caps = (const int*)d_in[1];
    const int* lens = (const int*)d_in[2];
    const float* W_enc = (const float*)d_in[3];
    const float* b_enc = (const float*)d_in[4];
    const float* W_dec = (const float*)d_in[5];
    const float* b_dec = (const float*)d_in[6];
    const float* W_full = (const float*)d_in[7];
    const float* b_full = (const float*)d_in[8];
    const float* W_init_h = (const float*)d_in[9];
    const float* b_init_h = (const float*)d_in[10];
    const float* W_init_c = (const float*)d_in[11];
    const float* b_init_c = (const float*)d_in[12];
    const float* W_fbeta = (const float*)d_in[13];
    const float* b_fbeta = (const float*)d_in[14];
    const float* W_fc = (const float*)d_in[15];
    const float* b_fc = (const float*)d_in[16];
    const float* emb_table = (const float*)d_in[17];
    const float* W_ih = (const float*)d_in[18];
    const float* b_ih = (const float*)d_in[19];
    const float* W_hh = (const float*)d_in[20];
    const float* b_hh = (const float*)d_in[21];
    float* out = (float*)d_out;

    char* p = (char*)d_ws;
    auto alloc = [&](size_t bytes) {
        void* r = (void*)p;
        p += (bytes + 255) & ~(size_t)255;
        return r;
    };
    int* order = (int*)alloc(Bsz * 4);
    int* lens_s = (int*)alloc(Bsz * 4);
    float* enc_s = (float*)alloc(Bsz * Edim * 4);
    float* att1 = (float*)alloc(Bsz * Adim * 4);
    float* h = (float*)alloc(Bsz * Ddim * 4);
    float* c = (float*)alloc(Bsz * Ddim * 4);
    float* att2 = (float*)alloc(Bsz * Adim * 4);
    float* gate = (float*)alloc(Bsz * Ddim * 4);
    float* hh = (float*)alloc(Bsz * 2048 * 4);
    float* x = (float*)alloc(Bsz * 1024 * 4);
    float* gates = (float*)alloc(Bsz * 2048 * 4);
    unsigned short* h_hist = (unsigned short*)alloc((size_t)Tlen * Bsz * 512 * 2);
    unsigned short* wfc16 = (unsigned short*)alloc((size_t)Vdim * Ddim * 2);

    k_sort<<<1, 128, 0, stream>>>(lens, order, lens_s);
    k_gather<<<Bsz, 256, 0, stream>>>(encoder_out, order, enc_s);
    k_cvtW<<<(Vdim * Ddim + 255) / 256, 256, 0, stream>>>(W_fc, wfc16, Vdim * Ddim);
    k_init<<<dim3(24, 2), 256, 0, stream>>>(enc_s, W_init_h, b_init_h, W_init_c,
                                            b_init_c, W_enc, b_enc, h, c, att1);
    for (int t = 0; t < Tlen; ++t) {
        k_stepA<<<dim3(48, 2), 256, 0, stream>>>(h, W_dec, b_dec, W_fbeta, b_fbeta,
                                                 W_hh, b_hh, att2, gate, hh);
        k_stepB<<<Bsz, 256, 0, stream>>>(att1, att2, enc_s, W_full, b_full, gate,
                                         emb_table, caps, order, lens_s, x, t);
        k_stepC<<<dim3(32, 2), 256, 0, stream>>>(x, W_ih, b_ih, hh, gates);
        k_lstm<<<256, 256, 0, stream>>>(gates, h, c, lens_s, h_hist, t);
    }
    k_preds<<<dim3(32, 96), 256, 0, stream>>>(h_hist, wfc16, b_fc, lens_s, out);
}